// Round 1
// baseline (82.988 us; speedup 1.0000x reference)
//
#include <hip/hip_runtime.h>

#define VOCAB 32000
#define NB 32
#define NS 32
#define NA 512

// General float atomic max via CAS on the int image. Cheap at 512K total ops.
__device__ __forceinline__ void atomicMaxFloat(float* addr, float val) {
    int* ia = (int*)addr;
    int old = __hip_atomic_load(ia, __ATOMIC_RELAXED, __HIP_MEMORY_SCOPE_AGENT);
    while (true) {
        float cur = __int_as_float(old);
        if (cur >= val) break;
        int assumed = old;
        old = atomicCAS(ia, assumed, __float_as_int(val));
        if (old == assumed) break;
    }
}

// Copy decoder_outputs -> out as float4, zeroing vocab index 1 of each row.
// VOCAB % 4 == 0, so a float4 never straddles a row; index 1 is .y of the
// float4 whose element base is row-aligned.
__global__ void copy_zero_kernel(const float4* __restrict__ in,
                                 float4* __restrict__ out, int n4) {
    int i = blockIdx.x * blockDim.x + threadIdx.x;
    const int stride = gridDim.x * blockDim.x;
    for (; i < n4; i += stride) {
        float4 v = in[i];
        // element base index of this float4 within its vocab row
        if (((i * 4) % VOCAB) == 0) v.y = 0.0f;
        out[i] = v;
    }
}

// One thread per (b,a): lookup mapped vocab id once, scatter-max across s.
__global__ void scatter_max_kernel(const float* __restrict__ att,    // (B,S,A)
                                   const int* __restrict__ seq,      // (B,A)
                                   const int* __restrict__ table,    // (SRC_VOCAB)
                                   float* __restrict__ out) {        // (B,S,VOCAB)
    int t = blockIdx.x * blockDim.x + threadIdx.x;
    if (t >= NB * NA) return;
    const int b = t / NA;
    const int a = t - b * NA;
    const int v = table[seq[t]];
    if (v == 1) return;  // overwritten by the final .at[:,:,1].set(0)
    float* outp = out + (size_t)b * NS * VOCAB + v;
    const float* attp = att + (size_t)b * NS * NA + a;
#pragma unroll
    for (int s = 0; s < NS; ++s) {
        atomicMaxFloat(outp + (size_t)s * VOCAB, attp[(size_t)s * NA]);
    }
}

extern "C" void kernel_launch(void* const* d_in, const int* in_sizes, int n_in,
                              void* d_out, int out_size, void* d_ws, size_t ws_size,
                              hipStream_t stream) {
    const float* decoder_outputs = (const float*)d_in[0];   // (32,32,32000) f32
    const float* attention_scores = (const float*)d_in[1];  // (32,32,512) f32
    const int* input_sequence = (const int*)d_in[2];        // (32,512) i32
    // d_in[3], d_in[4]: repeat_idx / repeat_idx2 — unused by the math
    const int* convert_table = (const int*)d_in[5];         // (50000,) i32
    float* out = (float*)d_out;                             // (32,32,32000) f32

    const int n4 = NB * NS * VOCAB / 4;  // 8,192,000 float4s
    copy_zero_kernel<<<2048, 256, 0, stream>>>(
        (const float4*)decoder_outputs, (float4*)out, n4);

    const int nscatter = NB * NA;  // 16384
    scatter_max_kernel<<<(nscatter + 255) / 256, 256, 0, stream>>>(
        attention_scores, input_sequence, convert_table, out);
}